// Round 6
// baseline (160.231 us; speedup 1.0000x reference)
//
#include <hip/hip_runtime.h>

typedef __attribute__((ext_vector_type(8))) __bf16 bf16x8;
typedef __attribute__((ext_vector_type(4))) __bf16 bf16x4;
typedef __attribute__((ext_vector_type(4))) float f32x4;

#define N_SAMP 256
#define DIM    2048
#define NCENT  32000
#define INV_T  14.285714285714285714f   // 1 / 0.07
#define NWG    500                       // 250 n-tiles x 2 m-tiles

// ---------------- kernel 1: row-normalize feats -> bf16; also zero d_acc ----------------
__global__ __launch_bounds__(256) void norm_kernel(const float* __restrict__ feats,
                                                   __bf16* __restrict__ fnorm,
                                                   float* __restrict__ d_acc) {
    int row = blockIdx.x;
    int tid = threadIdx.x;
    if (row < 16) d_acc[row * 256 + tid] = 0.f;   // zero 8 slots x 512 floats
    const float* src = feats + (size_t)row * DIM;
    float4 v0 = reinterpret_cast<const float4*>(src)[2 * tid];
    float4 v1 = reinterpret_cast<const float4*>(src)[2 * tid + 1];
    float ss = v0.x * v0.x + v0.y * v0.y + v0.z * v0.z + v0.w * v0.w
             + v1.x * v1.x + v1.y * v1.y + v1.z * v1.z + v1.w * v1.w;
    #pragma unroll
    for (int off = 1; off < 64; off <<= 1) ss += __shfl_xor(ss, off, 64);
    __shared__ float wsum[4];
    if ((tid & 63) == 0) wsum[tid >> 6] = ss;
    __syncthreads();
    float inv = 1.0f / sqrtf(wsum[0] + wsum[1] + wsum[2] + wsum[3]);
    bf16x8 o;
    o[0] = (__bf16)(v0.x * inv); o[1] = (__bf16)(v0.y * inv);
    o[2] = (__bf16)(v0.z * inv); o[3] = (__bf16)(v0.w * inv);
    o[4] = (__bf16)(v1.x * inv); o[5] = (__bf16)(v1.y * inv);
    o[6] = (__bf16)(v1.z * inv); o[7] = (__bf16)(v1.w * inv);
    *reinterpret_cast<bf16x8*>(fnorm + (size_t)row * DIM + tid * 8) = o;
}

// ------------- kernel 2: pipelined 128x128 GEMM -------------
// B (centers, f32): regs -> cvt -> swizzled LDS, depth-2, counted-vmcnt barriers.
// A (fnorm, bf16, L2-resident): direct global->reg fragments, 1-step prefetch.
__global__ __launch_bounds__(512, 4) void sims_kernel(
    const __bf16* __restrict__ fnorm, const float* __restrict__ centers,
    const int* __restrict__ labels, const int* __restrict__ camids,
    float* __restrict__ d_acc, float* __restrict__ d_own)
{
    __shared__ __align__(16) char sB[2][8192];   // 128 rows x 32 bf16 (64 B), swizzled

    const int tid  = threadIdx.x;
    const int wave = tid >> 6;
    const int lane = tid & 63;
    const int l15  = lane & 15;
    const int lhi  = lane >> 4;

    // bijective XCD swizzle (nwg=500: q=62, r=4); pairs (n, m=0/1) adjacent per XCD
    const int d   = blockIdx.x;
    const int xcd = d & 7, loc = d >> 3;
    const int lid = (xcd < 4 ? xcd * 63 : 252 + (xcd - 4) * 62) + loc;
    const int nb  = lid >> 1;     // 0..249 center tile (128 centers)
    const int mb  = lid & 1;      // 0..1   sample tile (128 samples)

    const int wr = (wave >> 2) * 64;   // wave rows within tile
    const int wc = (wave & 3) * 32;    // wave cols within tile

    f32x4 acc[4][2] = {};

    const float4* bsrc = reinterpret_cast<const float4*>(centers);
    const __bf16* abase = fnorm + (size_t)(mb * 128 + wr + l15) * DIM + lhi * 8;

    auto issueB = [&](int step, float4& b0, float4& b1) {
        int r0 = tid >> 3, p = tid & 7;
        b0 = bsrc[(size_t)(nb * 128 + r0) * 512 + step * 8 + p];
        int r1 = (512 + tid) >> 3;
        b1 = bsrc[(size_t)(nb * 128 + r1) * 512 + step * 8 + p];
    };
    auto issueA = [&](int step, bf16x8 (&af)[4]) {
        const __bf16* a0 = abase + step * 32;
        #pragma unroll
        for (int mi = 0; mi < 4; ++mi)
            af[mi] = *reinterpret_cast<const bf16x8*>(a0 + (size_t)mi * 16 * DIM);
    };
    auto wrbuf = [&](int b, const float4& b0, const float4& b1) {
        #pragma unroll
        for (int j = 0; j < 2; ++j) {
            const float4& v = j ? b1 : b0;
            int row = (j * 512 + tid) >> 3, pos = tid & 7;
            int adr = (row * 64 + pos * 8) ^ ((row & 7) << 4);
            bf16x4 o;
            o[0] = (__bf16)v.x; o[1] = (__bf16)v.y;
            o[2] = (__bf16)v.z; o[3] = (__bf16)v.w;
            *reinterpret_cast<uint2*>(&sB[b][adr]) = __builtin_bit_cast(uint2, o);
        }
    };
    auto compute = [&](int b, const bf16x8 (&af)[4]) {
        bf16x8 bf[2];
        #pragma unroll
        for (int ni = 0; ni < 2; ++ni) {
            int row = wc + ni * 16 + l15;
            int adr = (row * 64 + lhi * 16) ^ ((row & 7) << 4);
            bf[ni] = *reinterpret_cast<const bf16x8*>(&sB[b][adr]);
        }
        #pragma unroll
        for (int mi = 0; mi < 4; ++mi)
            #pragma unroll
            for (int ni = 0; ni < 2; ++ni)
                acc[mi][ni] = __builtin_amdgcn_mfma_f32_16x16x32_bf16(
                    af[mi], bf[ni], acc[mi][ni], 0, 0, 0);
    };
    #define BAR() do { asm volatile("s_waitcnt lgkmcnt(0)" ::: "memory"); \
                       __builtin_amdgcn_s_barrier(); } while (0)

    float4 b0A, b1A, b0B, b1B;
    bf16x8 afA[4], afB[4];

    issueB(0, b0A, b1A);
    issueB(1, b0B, b1B);
    issueA(0, afA);
    wrbuf(0, b0A, b1A);
    BAR();
    for (int t = 0; t < 64; t += 2) {
        if (t + 2 < 64) issueB(t + 2, b0A, b1A);
        issueA(t + 1, afB);
        compute(0, afA);
        wrbuf(1, b0B, b1B);              // waits vmcnt on set B only; set A stays in flight
        BAR();
        if (t + 3 < 64) issueB(t + 3, b0B, b1B);
        if (t + 2 < 64) issueA(t + 2, afA);
        compute(1, afB);
        if (t + 2 < 64) {
            wrbuf(0, b0A, b1A);
            BAR();
        }
    }

    // ---- epilogue: exp + masks + per-sample partial denominators ----
    float* slot = d_acc + (d & 7) * 512;
    #pragma unroll
    for (int mi = 0; mi < 4; ++mi) {
        #pragma unroll
        for (int r = 0; r < 4; ++r) {
            int i   = mb * 128 + wr + mi * 16 + lhi * 4 + r;
            int lab = labels[i], cam = camids[i];
            int oidx = lab * 8 + cam;
            float pi = 0.f, pj = 0.f;
            #pragma unroll
            for (int ni = 0; ni < 2; ++ni) {
                int c = nb * 128 + wc + ni * 16 + l15;
                float s = acc[mi][ni][r] * INV_T;
                float e = __expf(s);
                if ((l15 & 7) == cam) pi += e;          // c % 8 == cam
                bool ol = ((c >> 3) == lab);
                bool hard = (!ol) && (c < ((c < lab * 8) ? 50 : 58));
                if (ol || hard) pj += e;
                if (c == oidx) d_own[i] = s;
            }
            #pragma unroll
            for (int off = 1; off < 16; off <<= 1) {
                pi += __shfl_xor(pi, off, 64);
                pj += __shfl_xor(pj, off, 64);
            }
            if (l15 == 0) {
                atomicAdd(&slot[i], pi);
                atomicAdd(&slot[N_SAMP + i], pj);
            }
        }
    }
}

// ---------------- kernel 3: finalize (segment means + output) ----------------
__global__ __launch_bounds__(256) void finalize_kernel(
    const float* __restrict__ d_acc, const float* __restrict__ d_own,
    const int* __restrict__ labels, const int* __restrict__ camids,
    float* __restrict__ out, int out_size)
{
    __shared__ int s_lab[N_SAMP], s_cam[N_SAMP];
    __shared__ float wsum[8];
    int tid = threadIdx.x;
    s_lab[tid] = labels[tid];
    s_cam[tid] = camids[tid];
    __syncthreads();
    int myl = s_lab[tid], myc = s_cam[tid];
    int nl = 0, nc = 0;
    for (int j = 0; j < N_SAMP; ++j) {
        nl += (s_lab[j] == myl);
        nc += (s_cam[j] == myc);
    }
    float di = 0.f, dj = 0.f;
    #pragma unroll
    for (int s = 0; s < 8; ++s) {
        di += d_acc[s * 512 + tid];
        dj += d_acc[s * 512 + 256 + tid];
    }
    float own = d_own[tid];
    float li = own - logf(di);
    float lj = own - logf(dj);
    float a = li / (float)nc;   // sum_i loss_i / n_cam == sum over cams of per-cam mean
    float b = lj / (float)nl;
    #pragma unroll
    for (int off = 1; off < 64; off <<= 1) {
        a += __shfl_xor(a, off, 64);
        b += __shfl_xor(b, off, 64);
    }
    if ((tid & 63) == 0) { wsum[tid >> 6] = a; wsum[4 + (tid >> 6)] = b; }
    __syncthreads();
    if (tid == 0) {
        float sa = wsum[0] + wsum[1] + wsum[2] + wsum[3];
        float sb = wsum[4] + wsum[5] + wsum[6] + wsum[7];
        out[0] = -sa;
        if (out_size > 1) out[1] = -0.5f * sb;   // LAMDA = 0.5
    }
}

extern "C" void kernel_launch(void* const* d_in, const int* in_sizes, int n_in,
                              void* d_out, int out_size, void* d_ws, size_t ws_size,
                              hipStream_t stream) {
    const float* feats   = (const float*)d_in[0];
    const float* centers = (const float*)d_in[1];
    const int*   labels  = (const int*)d_in[2];
    const int*   camids  = (const int*)d_in[3];
    float* out = (float*)d_out;

    __bf16* fnorm = (__bf16*)d_ws;
    float* d_acc  = (float*)((char*)d_ws + (size_t)N_SAMP * DIM * sizeof(__bf16));
    float* d_own  = d_acc + 8 * 2 * N_SAMP;

    norm_kernel<<<N_SAMP, 256, 0, stream>>>(feats, fnorm, d_acc);
    sims_kernel<<<NWG, 512, 0, stream>>>(fnorm, centers, labels, camids, d_acc, d_own);
    finalize_kernel<<<1, 256, 0, stream>>>(d_acc, d_own, labels, camids, out, out_size);
}

// Round 7
// 90.870 us; speedup vs baseline: 1.7633x; 1.7633x over previous
//
#include <hip/hip_runtime.h>

typedef __attribute__((ext_vector_type(8))) __bf16 bf16x8;
typedef __attribute__((ext_vector_type(4))) __bf16 bf16x4;
typedef __attribute__((ext_vector_type(4))) float f32x4;

#define N_SAMP 256
#define DIM    2048
#define NCENT  32000
#define INV_T  14.285714285714285714f   // 1 / 0.07
#define NWG    500                       // 250 n-tiles x 2 m-tiles

// ---------------- kernel 1: row-normalize feats -> bf16; also zero d_acc ----------------
__global__ __launch_bounds__(256) void norm_kernel(const float* __restrict__ feats,
                                                   __bf16* __restrict__ fnorm,
                                                   float* __restrict__ d_acc) {
    int row = blockIdx.x;
    int tid = threadIdx.x;
    if (row < 16) d_acc[row * 256 + tid] = 0.f;   // zero 8 slots x 512 floats
    const float* src = feats + (size_t)row * DIM;
    float4 v0 = reinterpret_cast<const float4*>(src)[2 * tid];
    float4 v1 = reinterpret_cast<const float4*>(src)[2 * tid + 1];
    float ss = v0.x * v0.x + v0.y * v0.y + v0.z * v0.z + v0.w * v0.w
             + v1.x * v1.x + v1.y * v1.y + v1.z * v1.z + v1.w * v1.w;
    #pragma unroll
    for (int off = 1; off < 64; off <<= 1) ss += __shfl_xor(ss, off, 64);
    __shared__ float wsum[4];
    if ((tid & 63) == 0) wsum[tid >> 6] = ss;
    __syncthreads();
    float inv = 1.0f / sqrtf(wsum[0] + wsum[1] + wsum[2] + wsum[3]);
    bf16x8 o;
    o[0] = (__bf16)(v0.x * inv); o[1] = (__bf16)(v0.y * inv);
    o[2] = (__bf16)(v0.z * inv); o[3] = (__bf16)(v0.w * inv);
    o[4] = (__bf16)(v1.x * inv); o[5] = (__bf16)(v1.y * inv);
    o[6] = (__bf16)(v1.z * inv); o[7] = (__bf16)(v1.w * inv);
    *reinterpret_cast<bf16x8*>(fnorm + (size_t)row * DIM + tid * 8) = o;
}

// ------------- kernel 2: pipelined 128x128 GEMM, depth-4 prefetch -------------
// A (fnorm bf16) and B (centers f32->cvt) staged regs -> swizzled LDS.
// 4 named register sets; each set is in flight 3 K-steps (~900+ cy) before its
// LDS write. Raw s_barrier with lgkmcnt(0)-only drain keeps vmcnt counted.
__global__ __launch_bounds__(512, 4) void sims_kernel(
    const __bf16* __restrict__ fnorm, const float* __restrict__ centers,
    const int* __restrict__ labels, const int* __restrict__ camids,
    float* __restrict__ d_acc, float* __restrict__ d_own)
{
    __shared__ __align__(16) char sA[2][8192];   // 128 rows x 32 bf16 (64 B), swizzled
    __shared__ __align__(16) char sB[2][8192];

    const int tid  = threadIdx.x;
    const int wave = tid >> 6;
    const int lane = tid & 63;
    const int l15  = lane & 15;
    const int lhi  = lane >> 4;

    // bijective XCD swizzle (nwg=500: q=62, r=4); pairs (n, m=0/1) adjacent per XCD
    const int d   = blockIdx.x;
    const int xcd = d & 7, loc = d >> 3;
    const int lid = (xcd < 4 ? xcd * 63 : 252 + (xcd - 4) * 62) + loc;
    const int nb  = lid >> 1;     // 0..249 center tile (128 centers)
    const int mb  = lid & 1;      // 0..1   sample tile (128 samples)

    const int wr = (wave >> 2) * 64;   // wave rows within tile
    const int wc = (wave & 3) * 32;    // wave cols within tile

    f32x4 acc[4][2] = {};

    const float4* bsrc = reinterpret_cast<const float4*>(centers);
    const uint4*  asrc = reinterpret_cast<const uint4*>(fnorm);

    auto issue = [&](int step, float4& b0, float4& b1, uint4& a) {
        int r0 = tid >> 3, p = tid & 7;
        b0 = bsrc[(size_t)(nb * 128 + r0) * 512 + step * 8 + p];
        int r1 = 64 + (tid >> 3);
        b1 = bsrc[(size_t)(nb * 128 + r1) * 512 + step * 8 + p];
        int ra = tid >> 2, pa = tid & 3;
        a = asrc[(size_t)(mb * 128 + ra) * 256 + step * 4 + pa];
    };
    auto wrbuf = [&](int b, const float4& b0, const float4& b1, const uint4& a) {
        #pragma unroll
        for (int j = 0; j < 2; ++j) {
            const float4& v = j ? b1 : b0;
            int row = j * 64 + (tid >> 3), pos = tid & 7;
            int adr = (row * 64 + pos * 8) ^ ((row & 7) << 4);
            bf16x4 o;
            o[0] = (__bf16)v.x; o[1] = (__bf16)v.y;
            o[2] = (__bf16)v.z; o[3] = (__bf16)v.w;
            *reinterpret_cast<uint2*>(&sB[b][adr]) = __builtin_bit_cast(uint2, o);
        }
        {
            int row = tid >> 2, pos = tid & 3;
            int adr = (row * 64 + pos * 16) ^ ((row & 7) << 4);
            *reinterpret_cast<uint4*>(&sA[b][adr]) = a;
        }
    };
    auto compute = [&](int b) {
        bf16x8 af[4], bf[2];
        #pragma unroll
        for (int mi = 0; mi < 4; ++mi) {
            int row = wr + mi * 16 + l15;
            int adr = (row * 64 + lhi * 16) ^ ((row & 7) << 4);
            af[mi] = *reinterpret_cast<const bf16x8*>(&sA[b][adr]);
        }
        #pragma unroll
        for (int ni = 0; ni < 2; ++ni) {
            int row = wc + ni * 16 + l15;
            int adr = (row * 64 + lhi * 16) ^ ((row & 7) << 4);
            bf[ni] = *reinterpret_cast<const bf16x8*>(&sB[b][adr]);
        }
        #pragma unroll
        for (int mi = 0; mi < 4; ++mi)
            #pragma unroll
            for (int ni = 0; ni < 2; ++ni)
                acc[mi][ni] = __builtin_amdgcn_mfma_f32_16x16x32_bf16(
                    af[mi], bf[ni], acc[mi][ni], 0, 0, 0);
    };
    #define BAR() do { asm volatile("s_waitcnt lgkmcnt(0)" ::: "memory"); \
                       __builtin_amdgcn_s_barrier(); } while (0)

    // 4 named register sets (static indexing, no arrays)
    float4 b0S0, b1S0, b0S1, b1S1, b0S2, b1S2, b0S3, b1S3;
    uint4  aS0, aS1, aS2, aS3;

    issue(0, b0S0, b1S0, aS0);
    issue(1, b0S1, b1S1, aS1);
    issue(2, b0S2, b1S2, aS2);
    issue(3, b0S3, b1S3, aS3);
    wrbuf(0, b0S0, b1S0, aS0);
    BAR();

    // steady state: 16 iterations x 4 steps. At step t (=4i+p):
    //   issue(t+4) into set[p], compute(buf[p&1]), wrbuf(buf[(p+1)&1], set[(p+1)&3])
    for (int i = 0; i < 16; ++i) {
        int t = i * 4;
        bool pf = (i < 15);
        if (pf) issue(t + 4, b0S0, b1S0, aS0);
        compute(0);
        wrbuf(1, b0S1, b1S1, aS1);          // set issued 3 steps ago -> vmcnt(9)
        BAR();
        if (pf) issue(t + 5, b0S1, b1S1, aS1);
        compute(1);
        wrbuf(0, b0S2, b1S2, aS2);
        BAR();
        if (pf) issue(t + 6, b0S2, b1S2, aS2);
        compute(0);
        wrbuf(1, b0S3, b1S3, aS3);
        BAR();
        if (pf) issue(t + 7, b0S3, b1S3, aS3);
        compute(1);
        if (pf) {
            wrbuf(0, b0S0, b1S0, aS0);
            BAR();
        }
    }

    // ---- epilogue: exp + masks + per-sample partial denominators ----
    float* slot = d_acc + (d & 7) * 512;
    #pragma unroll
    for (int mi = 0; mi < 4; ++mi) {
        #pragma unroll
        for (int r = 0; r < 4; ++r) {
            int i   = mb * 128 + wr + mi * 16 + lhi * 4 + r;
            int lab = labels[i], cam = camids[i];
            int oidx = lab * 8 + cam;
            float pi = 0.f, pj = 0.f;
            #pragma unroll
            for (int ni = 0; ni < 2; ++ni) {
                int c = nb * 128 + wc + ni * 16 + l15;
                float s = acc[mi][ni][r] * INV_T;
                float e = __expf(s);
                if ((l15 & 7) == cam) pi += e;          // c % 8 == cam
                bool ol = ((c >> 3) == lab);
                bool hard = (!ol) && (c < ((c < lab * 8) ? 50 : 58));
                if (ol || hard) pj += e;
                if (c == oidx) d_own[i] = s;
            }
            #pragma unroll
            for (int off = 1; off < 16; off <<= 1) {
                pi += __shfl_xor(pi, off, 64);
                pj += __shfl_xor(pj, off, 64);
            }
            if (l15 == 0) {
                atomicAdd(&slot[i], pi);
                atomicAdd(&slot[N_SAMP + i], pj);
            }
        }
    }
}

// ---------------- kernel 3: finalize (segment means + output) ----------------
__global__ __launch_bounds__(256) void finalize_kernel(
    const float* __restrict__ d_acc, const float* __restrict__ d_own,
    const int* __restrict__ labels, const int* __restrict__ camids,
    float* __restrict__ out, int out_size)
{
    __shared__ int s_lab[N_SAMP], s_cam[N_SAMP];
    __shared__ float wsum[8];
    int tid = threadIdx.x;
    s_lab[tid] = labels[tid];
    s_cam[tid] = camids[tid];
    __syncthreads();
    int myl = s_lab[tid], myc = s_cam[tid];
    int nl = 0, nc = 0;
    for (int j = 0; j < N_SAMP; ++j) {
        nl += (s_lab[j] == myl);
        nc += (s_cam[j] == myc);
    }
    float di = 0.f, dj = 0.f;
    #pragma unroll
    for (int s = 0; s < 8; ++s) {
        di += d_acc[s * 512 + tid];
        dj += d_acc[s * 512 + 256 + tid];
    }
    float own = d_own[tid];
    float li = own - logf(di);
    float lj = own - logf(dj);
    float a = li / (float)nc;   // sum_i loss_i / n_cam == sum over cams of per-cam mean
    float b = lj / (float)nl;
    #pragma unroll
    for (int off = 1; off < 64; off <<= 1) {
        a += __shfl_xor(a, off, 64);
        b += __shfl_xor(b, off, 64);
    }
    if ((tid & 63) == 0) { wsum[tid >> 6] = a; wsum[4 + (tid >> 6)] = b; }
    __syncthreads();
    if (tid == 0) {
        float sa = wsum[0] + wsum[1] + wsum[2] + wsum[3];
        float sb = wsum[4] + wsum[5] + wsum[6] + wsum[7];
        out[0] = -sa;
        if (out_size > 1) out[1] = -0.5f * sb;   // LAMDA = 0.5
    }
}

extern "C" void kernel_launch(void* const* d_in, const int* in_sizes, int n_in,
                              void* d_out, int out_size, void* d_ws, size_t ws_size,
                              hipStream_t stream) {
    const float* feats   = (const float*)d_in[0];
    const float* centers = (const float*)d_in[1];
    const int*   labels  = (const int*)d_in[2];
    const int*   camids  = (const int*)d_in[3];
    float* out = (float*)d_out;

    __bf16* fnorm = (__bf16*)d_ws;
    float* d_acc  = (float*)((char*)d_ws + (size_t)N_SAMP * DIM * sizeof(__bf16));
    float* d_own  = d_acc + 8 * 2 * N_SAMP;

    norm_kernel<<<N_SAMP, 256, 0, stream>>>(feats, fnorm, d_acc);
    sims_kernel<<<NWG, 512, 0, stream>>>(fnorm, centers, labels, camids, d_acc, d_own);
    finalize_kernel<<<1, 256, 0, stream>>>(d_acc, d_own, labels, camids, out, out_size);
}

// Round 9
// 86.052 us; speedup vs baseline: 1.8620x; 1.0560x over previous
//
#include <hip/hip_runtime.h>

typedef __attribute__((ext_vector_type(8))) __bf16 bf16x8;
typedef __attribute__((ext_vector_type(4))) __bf16 bf16x4;
typedef __attribute__((ext_vector_type(4))) float f32x4;

#define N_SAMP 256
#define DIM    2048
#define NCENT  32000
#define INV_T  14.285714285714285714f   // 1 / 0.07
#define NWG    250                       // one 256x128 tile per block

// ---------------- kernel 1: row-normalize feats -> bf16; also zero d_acc ----------------
__global__ __launch_bounds__(256) void norm_kernel(const float* __restrict__ feats,
                                                   __bf16* __restrict__ fnorm,
                                                   float* __restrict__ d_acc) {
    int row = blockIdx.x;
    int tid = threadIdx.x;
    if (row < 16) d_acc[row * 256 + tid] = 0.f;   // zero 8 slots x 512 floats
    const float* src = feats + (size_t)row * DIM;
    float4 v0 = reinterpret_cast<const float4*>(src)[2 * tid];
    float4 v1 = reinterpret_cast<const float4*>(src)[2 * tid + 1];
    float ss = v0.x * v0.x + v0.y * v0.y + v0.z * v0.z + v0.w * v0.w
             + v1.x * v1.x + v1.y * v1.y + v1.z * v1.z + v1.w * v1.w;
    #pragma unroll
    for (int off = 1; off < 64; off <<= 1) ss += __shfl_xor(ss, off, 64);
    __shared__ float wsum[4];
    if ((tid & 63) == 0) wsum[tid >> 6] = ss;
    __syncthreads();
    float inv = 1.0f / sqrtf(wsum[0] + wsum[1] + wsum[2] + wsum[3]);
    bf16x8 o;
    o[0] = (__bf16)(v0.x * inv); o[1] = (__bf16)(v0.y * inv);
    o[2] = (__bf16)(v0.z * inv); o[3] = (__bf16)(v0.w * inv);
    o[4] = (__bf16)(v1.x * inv); o[5] = (__bf16)(v1.y * inv);
    o[6] = (__bf16)(v1.z * inv); o[7] = (__bf16)(v1.w * inv);
    *reinterpret_cast<bf16x8*>(fnorm + (size_t)row * DIM + tid * 8) = o;
}

// ------------- kernel 2: 256x128-tile pipelined GEMM + masked reduce -------------
// 250 blocks x 512 threads (8 waves = 4m x 2n; wave tile 64x64, acc 4x4).
// BK=32. A (full 256 rows of fnorm) + B (128 centers) staged regs -> swizzled
// LDS, depth-2 named register sets, raw s_barrier with lgkmcnt(0)-only drain
// (vmcnt stays counted -> prefetch loads live across barriers).
__global__ __launch_bounds__(512, 2) void sims_kernel(
    const __bf16* __restrict__ fnorm, const float* __restrict__ centers,
    const int* __restrict__ labels, const int* __restrict__ camids,
    float* __restrict__ d_acc, float* __restrict__ d_own)
{
    __shared__ __align__(16) char sA[2][16384];  // 256 rows x 32 bf16 (64 B), swizzled
    __shared__ __align__(16) char sB[2][8192];   // 128 rows x 32 bf16 (64 B), swizzled

    const int tid  = threadIdx.x;
    const int wave = tid >> 6;
    const int lane = tid & 63;
    const int l15  = lane & 15;
    const int lhi  = lane >> 4;

    const int nb    = blockIdx.x;       // 0..249 center tile (128 centers)
    const int cbase = nb * 128;

    const int wr = (wave >> 1) * 64;    // wave rows within 256-row tile
    const int wc = (wave & 1) * 64;     // wave cols within 128-col tile

    f32x4 acc[4][4] = {};

    const float4* bsrc = reinterpret_cast<const float4*>(centers);
    const uint4*  asrc = reinterpret_cast<const uint4*>(fnorm);

    // B: f = j*512+tid: row=f>>3 (0..127), pos=f&7 (8 float4 = 32 f32/row)
    // A: s = j*512+tid: row=s>>2 (0..255), pos=s&3 (4 uint4 = 32 bf16/row)
    auto issue = [&](int step, float4& b0, float4& b1, uint4& a0, uint4& a1) {
        int rb0 = tid >> 3, p = tid & 7;
        b0 = bsrc[(size_t)(cbase + rb0) * 512 + step * 8 + p];
        int rb1 = 64 + rb0;
        b1 = bsrc[(size_t)(cbase + rb1) * 512 + step * 8 + p];
        int ra0 = tid >> 2, pa = tid & 3;
        a0 = asrc[(size_t)ra0 * 256 + step * 4 + pa];
        int ra1 = 128 + ra0;
        a1 = asrc[(size_t)ra1 * 256 + step * 4 + pa];
    };
    auto wrbuf = [&](int b, const float4& b0, const float4& b1,
                     const uint4& a0, const uint4& a1) {
        #pragma unroll
        for (int j = 0; j < 2; ++j) {
            const float4& v = j ? b1 : b0;
            int row = j * 64 + (tid >> 3), pos = tid & 7;
            int adr = (row * 64 + pos * 8) ^ ((row & 7) << 4);
            bf16x4 o;
            o[0] = (__bf16)v.x; o[1] = (__bf16)v.y;
            o[2] = (__bf16)v.z; o[3] = (__bf16)v.w;
            *reinterpret_cast<uint2*>(&sB[b][adr]) = __builtin_bit_cast(uint2, o);
        }
        #pragma unroll
        for (int j = 0; j < 2; ++j) {
            const uint4& v = j ? a1 : a0;
            int row = j * 128 + (tid >> 2), pos = tid & 3;
            int adr = (row * 64 + pos * 16) ^ ((row & 7) << 4);
            *reinterpret_cast<uint4*>(&sA[b][adr]) = v;
        }
    };
    auto compute = [&](int b) {
        bf16x8 af[4], bf[4];
        #pragma unroll
        for (int mi = 0; mi < 4; ++mi) {
            int row = wr + mi * 16 + l15;
            int adr = (row * 64 + lhi * 16) ^ ((row & 7) << 4);
            af[mi] = *reinterpret_cast<const bf16x8*>(&sA[b][adr]);
        }
        #pragma unroll
        for (int ni = 0; ni < 4; ++ni) {
            int row = wc + ni * 16 + l15;
            int adr = (row * 64 + lhi * 16) ^ ((row & 7) << 4);
            bf[ni] = *reinterpret_cast<const bf16x8*>(&sB[b][adr]);
        }
        #pragma unroll
        for (int mi = 0; mi < 4; ++mi)
            #pragma unroll
            for (int ni = 0; ni < 4; ++ni)
                acc[mi][ni] = __builtin_amdgcn_mfma_f32_16x16x32_bf16(
                    af[mi], bf[ni], acc[mi][ni], 0, 0, 0);
    };
    #define BAR() do { asm volatile("s_waitcnt lgkmcnt(0)" ::: "memory"); \
                       __builtin_amdgcn_s_barrier(); } while (0)

    float4 b0A, b1A, b0B, b1B;
    uint4  a0A, a1A, a0B, a1B;

    issue(0, b0A, b1A, a0A, a1A);
    issue(1, b0B, b1B, a0B, a1B);
    wrbuf(0, b0A, b1A, a0A, a1A);
    BAR();
    for (int t = 0; t < 64; t += 2) {
        if (t + 2 < 64) issue(t + 2, b0A, b1A, a0A, a1A);
        compute(0);
        wrbuf(1, b0B, b1B, a0B, a1B);    // waits only set B; set A stays in flight
        BAR();
        if (t + 3 < 64) issue(t + 3, b0B, b1B, a0B, a1B);
        compute(1);
        if (t + 2 < 64) {
            wrbuf(0, b0A, b1A, a0A, a1A);
            BAR();
        }
    }

    // ---- epilogue: exp + masks + per-sample partial denominators ----
    float* slot = d_acc + (nb & 7) * 512;
    #pragma unroll
    for (int mi = 0; mi < 4; ++mi) {
        #pragma unroll
        for (int r = 0; r < 4; ++r) {
            int i   = wr + mi * 16 + lhi * 4 + r;
            int lab = labels[i], cam = camids[i];
            int oidx = lab * 8 + cam;
            float pi = 0.f, pj = 0.f;
            #pragma unroll
            for (int ni = 0; ni < 4; ++ni) {
                int c = cbase + wc + ni * 16 + l15;
                float s = acc[mi][ni][r] * INV_T;
                float e = __expf(s);
                if ((l15 & 7) == cam) pi += e;          // c % 8 == cam
                bool ol = ((c >> 3) == lab);
                bool hard = (!ol) && (c < ((c < lab * 8) ? 50 : 58));
                if (ol || hard) pj += e;
                if (c == oidx) d_own[i] = s;
            }
            #pragma unroll
            for (int off = 1; off < 16; off <<= 1) {
                pi += __shfl_xor(pi, off, 64);
                pj += __shfl_xor(pj, off, 64);
            }
            if (l15 == 0) {
                atomicAdd(&slot[i], pi);
                atomicAdd(&slot[N_SAMP + i], pj);
            }
        }
    }
}

// ---------------- kernel 3: finalize (segment means + output) ----------------
__global__ __launch_bounds__(256) void finalize_kernel(
    const float* __restrict__ d_acc, const float* __restrict__ d_own,
    const int* __restrict__ labels, const int* __restrict__ camids,
    float* __restrict__ out, int out_size)
{
    __shared__ int s_lab[N_SAMP], s_cam[N_SAMP];
    __shared__ float wsum[8];
    int tid = threadIdx.x;
    s_lab[tid] = labels[tid];
    s_cam[tid] = camids[tid];
    __syncthreads();
    int myl = s_lab[tid], myc = s_cam[tid];
    int nl = 0, nc = 0;
    for (int j = 0; j < N_SAMP; ++j) {
        nl += (s_lab[j] == myl);
        nc += (s_cam[j] == myc);
    }
    float di = 0.f, dj = 0.f;
    #pragma unroll
    for (int s = 0; s < 8; ++s) {
        di += d_acc[s * 512 + tid];
        dj += d_acc[s * 512 + 256 + tid];
    }
    float own = d_own[tid];
    float li = own - logf(di);
    float lj = own - logf(dj);
    float a = li / (float)nc;   // sum_i loss_i / n_cam == sum over cams of per-cam mean
    float b = lj / (float)nl;
    #pragma unroll
    for (int off = 1; off < 64; off <<= 1) {
        a += __shfl_xor(a, off, 64);
        b += __shfl_xor(b, off, 64);
    }
    if ((tid & 63) == 0) { wsum[tid >> 6] = a; wsum[4 + (tid >> 6)] = b; }
    __syncthreads();
    if (tid == 0) {
        float sa = wsum[0] + wsum[1] + wsum[2] + wsum[3];
        float sb = wsum[4] + wsum[5] + wsum[6] + wsum[7];
        out[0] = -sa;
        if (out_size > 1) out[1] = -0.5f * sb;   // LAMDA = 0.5
    }
}

extern "C" void kernel_launch(void* const* d_in, const int* in_sizes, int n_in,
                              void* d_out, int out_size, void* d_ws, size_t ws_size,
                              hipStream_t stream) {
    const float* feats   = (const float*)d_in[0];
    const float* centers = (const float*)d_in[1];
    const int*   labels  = (const int*)d_in[2];
    const int*   camids  = (const int*)d_in[3];
    float* out = (float*)d_out;

    __bf16* fnorm = (__bf16*)d_ws;
    float* d_acc  = (float*)((char*)d_ws + (size_t)N_SAMP * DIM * sizeof(__bf16));
    float* d_own  = d_acc + 8 * 2 * N_SAMP;

    norm_kernel<<<N_SAMP, 256, 0, stream>>>(feats, fnorm, d_acc);
    sims_kernel<<<NWG, 512, 0, stream>>>(fnorm, centers, labels, camids, d_acc, d_own);
    finalize_kernel<<<1, 256, 0, stream>>>(d_acc, d_own, labels, camids, out, out_size);
}